// Round 9
// baseline (334.231 us; speedup 1.0000x reference)
//
#include <hip/hip_runtime.h>
#include <cstdint>
#include <cstddef>

// B=4, S=2048, D=1024, U=1024 self-attention, fp32 in/out.
// R16 = R15 (scores/QK on 256x128 2-blk/CU k_gemm256) + NEW k_gemm64:
//       128x64-tile, 4-wave, single-buffered 2-barrier kernel for PV and
//       V-proj at 4 blocks/CU (1024-block grids). Diagnosis: PV (81us,
//       424 TF) and V-proj (40us, 430 TF) ran the 128^2 kernel at 2 blk/CU
//       -- the m97 structure's occupancy cliff. 128x64 tiles double the
//       grid to 1024 = 4/CU where that structure reaches ~850 TF.
//       Old k_gemm deleted (template hygiene). GEMM-core rounds stopped:
//       3 schedule variants all pinned at 36-38% MfmaUtil (R13-R15).

typedef unsigned short ushort_t;
typedef _Float16 half_t;
typedef __attribute__((ext_vector_type(8))) short short8;
typedef __attribute__((ext_vector_type(4))) float floatx4;

__device__ inline unsigned short h2u(half_t h) {
  union { half_t h; unsigned short u; } v; v.h = h; return v.u;
}

// async 16B global -> LDS (DMA). LDS dest = wave-uniform base + lane*16 (HW).
__device__ __forceinline__ void gload16(const half_t* g, half_t* l) {
  __builtin_amdgcn_global_load_lds(
      (const __attribute__((address_space(1))) unsigned int*)g,
      (__attribute__((address_space(3))) unsigned int*)l, 16, 0, 0);
}

#define BAR() asm volatile("s_barrier" ::: "memory")
#define LGKM0() asm volatile("s_waitcnt lgkmcnt(0)" ::: "memory")
#define VM3() asm volatile("s_waitcnt vmcnt(3)" ::: "memory")
#define VM0() asm volatile("s_waitcnt vmcnt(0)" ::: "memory")

// ---------- constants ----------
#define MX 8192       // B*S
#define KCAT 2048     // 2*D (fp16 2-term split-concatenated K dim)

// ws byte offsets (regions reused across phases; S overwrites xcat/wt)
#define XCAT_OFF 0UL                  // half [8192][2048] = 33554432 B
#define WT_OFF   50331648UL           // half 3 x [1024][2048] = 12582912 B
#define S_OFF    0UL                  // float [4][2048][2048] = 67108864 B
#define QCAT_OFF 69206016UL           // half [8192][2048]
#define KCAT_OFF 119537664UL          // half [8192][2048]
#define VT_OFF   169869312UL          // half [4][1024][2048] = 16777216 B
#define WS_NEED  186646528UL

// XCD remap, gridDim.x == 16, 512 blocks (k_gemm256): 4x16 rectangles/XCD.
// xj_ = physical_linear_id % 8 (16 = 0 mod 8). Bijective (9 bits).
#define XCD_REMAP16(BX, BY, BZ)                                             \
  const int fb_ = blockIdx.x + 16 * (blockIdx.y + gridDim.y * blockIdx.z);  \
  const int xj_ = fb_ & 7, xi_ = fb_ >> 3;                                  \
  const int BX = (xj_ & 3) * 4 + (xi_ & 3);                                 \
  const int nr_ = (xj_ >> 2) * 16 + (xi_ >> 2);                             \
  const int BY = nr_ % gridDim.y;                                           \
  const int BZ = nr_ / gridDim.y;

// XCD remap, gridDim.x == 16, 1024 blocks (k_gemm64). Bijective (10 bits):
// BX from (xj&3, xi&3); row from (xj>>2)*32 + (xi>>2), xi in [0,128).
#define XCD_REMAP1K(BX, BY, BZ)                                             \
  const int fb_ = blockIdx.x + 16 * (blockIdx.y + gridDim.y * blockIdx.z);  \
  const int xj_ = fb_ & 7, xi_ = fb_ >> 3;                                  \
  const int BX = (xj_ & 3) * 4 + (xi_ & 3);                                 \
  const int nr_ = (xj_ >> 2) * 32 + (xi_ >> 2);                             \
  const int BY = nr_ % gridDim.y;                                           \
  const int BZ = nr_ / gridDim.y;

// ---------- K1a: split inputs X -> Xcat = [xh | xl] (fp16) ----------
__global__ __launch_bounds__(256) void k_split_x(const float* __restrict__ X,
                                                 half_t* __restrict__ xcat) {
  long long i = (long long)blockIdx.x * 256 + threadIdx.x;  // over 8192*1024
  float x = X[i];
  half_t h = (half_t)x;
  half_t lo = (half_t)(x - (float)h);
  long long row = i >> 10;
  int col = (int)(i & 1023);
  half_t* r = xcat + row * KCAT;
  r[col] = h;
  r[col + 1024] = lo;
}

// ---------- K1b: transpose W -> WT_cat = [Wh | Wh] per weight ----------
__global__ __launch_bounds__(256) void k_split_wt(const float* __restrict__ Wq,
                                                  const float* __restrict__ Wk,
                                                  const float* __restrict__ Wv,
                                                  half_t* __restrict__ wt) {
  __shared__ float tile[64][65];
  const float* W = (blockIdx.z == 0) ? Wq : ((blockIdx.z == 1) ? Wk : Wv);
  half_t* out = wt + (size_t)blockIdx.z * 1024 * KCAT;
  int d0 = blockIdx.y * 64, u0 = blockIdx.x * 64;
  int t = threadIdx.x;
  int tr = t >> 6, tc = t & 63;
  for (int r = 0; r < 64; r += 4)
    tile[r + tr][tc] = W[(size_t)(d0 + r + tr) * 1024 + (u0 + tc)];
  __syncthreads();
  for (int r = 0; r < 64; r += 4) {
    int urow = r + tr, dcol = tc;
    float x = tile[dcol][urow];  // = WT[u0+urow][d0+dcol]
    half_t h = (half_t)x;
    half_t* o = out + (size_t)(u0 + urow) * KCAT + d0;
    o[dcol] = h;
    o[dcol + 1024] = h;
  }
}

enum { EP_F32 = 0, EP_QK = 1, EP_VT = 2 };

// ---------- 128x64 GEMM, single-buffered 2-barrier, 4 blocks/CU ----------
// 4 waves, wave tile 64x32 (acc[4][2] frags of 16x16x32). LDS 24 KB.
// Same m97-class structure as the old 128^2 kernel, retiled so PV/V-proj
// grids reach 1024 blocks = 4 blocks/CU (implicit cross-block overlap).
template <int MODE>
__global__ __launch_bounds__(256, 4) void k_gemm64(
    const half_t* __restrict__ A, long long aBatch, int lda,
    const half_t* __restrict__ Bt, long long bBatch, int ldb,
    void* __restrict__ Cout, long long cBatch, int ldc, int K) {
  __shared__ __align__(16) half_t As[128 * 64];  // 16 KB
  __shared__ __align__(16) half_t Bs[64 * 64];   // 8 KB
  const int t = threadIdx.x;
  XCD_REMAP1K(bx, by, z);
  A += (long long)z * aBatch;
  Bt += (long long)z * bBatch;
  const int m0 = by * 128, n0 = bx * 64;

  const int w = t >> 6, l = t & 63;
  const int lr = l & 15, quad = l >> 4;
  const int wm = (w >> 1) * 64, wn = (w & 1) * 32;

  const floatx4 fz = {0.f, 0.f, 0.f, 0.f};
  floatx4 acc[4][2];
#pragma unroll
  for (int i = 0; i < 4; i++)
#pragma unroll
    for (int j = 0; j < 2; j++) acc[i][j] = fz;

  // A staging: 1024 chunks, 4/thread: c = s*256+t, row=c>>3, gq=(c&7)^(row&7)
  // B staging: 512 chunks, 2/thread.
  const half_t* Ap[4];
  half_t* ldsA[4];
#pragma unroll
  for (int s = 0; s < 4; s++) {
    int c = s * 256 + t;
    int row = c >> 3, gq = (c & 7) ^ ((c >> 3) & 7);
    Ap[s] = A + (long long)(m0 + row) * lda + gq * 8;
    ldsA[s] = &As[(s * 256 + w * 64) * 8];
  }
  const half_t* Bp[2];
  half_t* ldsB[2];
#pragma unroll
  for (int s = 0; s < 2; s++) {
    int c = s * 256 + t;
    int row = c >> 3, gq = (c & 7) ^ ((c >> 3) & 7);
    Bp[s] = Bt + (long long)(n0 + row) * ldb + gq * 8;
    ldsB[s] = &Bs[(s * 256 + w * 64) * 8];
  }

  const int p0 = quad ^ (lr & 7);
  const int p1 = (quad + 4) ^ (lr & 7);
  const int arow = (wm + lr) * 64, brow = (wn + lr) * 64;

  for (int kb = 0; kb < K; kb += 64) {
    __syncthreads();
#pragma unroll
    for (int s = 0; s < 4; s++) gload16(Ap[s] + kb, ldsA[s]);
#pragma unroll
    for (int s = 0; s < 2; s++) gload16(Bp[s] + kb, ldsB[s]);
    __syncthreads();
#pragma unroll
    for (int s = 0; s < 2; s++) {
      const int pp = s ? p1 : p0;
      short8 af[4], bfg[2];
#pragma unroll
      for (int j = 0; j < 2; j++) bfg[j] = *(const short8*)&Bs[brow + j * 1024 + pp * 8];
#pragma unroll
      for (int i = 0; i < 4; i++) af[i] = *(const short8*)&As[arow + i * 1024 + pp * 8];
#pragma unroll
      for (int i = 0; i < 4; i++)
#pragma unroll
        for (int j = 0; j < 2; j++)
          acc[i][j] = __builtin_amdgcn_mfma_f32_16x16x32_f16(af[i], bfg[j], acc[i][j], 0, 0, 0);
    }
  }

#pragma unroll
  for (int i = 0; i < 4; i++) {
#pragma unroll
    for (int j = 0; j < 2; j++) {
#pragma unroll
      for (int r = 0; r < 4; r++) {
        int grow = m0 + wm + i * 16 + quad * 4 + r;
        int gcol = n0 + wn + j * 16 + lr;
        float v = acc[i][j][r];
        if (MODE == EP_F32) {
          float* C = (float*)Cout + (long long)z * cBatch;
          C[(long long)grow * ldc + gcol] = v;
        } else {  // EP_VT: V^T[b][u][s] = V[b*2048+s][u]
          half_t* C = (half_t*)Cout;
          int b = grow >> 11, s = grow & 2047;
          C[((long long)b * 1024 + gcol) * 2048 + s] = (half_t)v;
        }
      }
    }
  }
}

// ---------- 256x128 GEMM, 3-buffer 1-barrier-per-tile, 2 blocks/CU ----------
// (R15, unchanged) 8 waves (4m x 2n), 64x64/wave, BK=32, LDS 72 KB.
template <int MODE>
__global__ __launch_bounds__(512, 4) void k_gemm256(
    const half_t* __restrict__ A, long long aBatch, int lda,
    const half_t* __restrict__ Bt, long long bBatch, int ldb,
    void* __restrict__ Cout, long long cBatch, int ldc, int K,
    half_t* __restrict__ CoutK) {
  __shared__ __align__(16) half_t As[24576];  // [3][256][32]
  __shared__ __align__(16) half_t Bs[12288];  // [3][128][32]
  const int tid = threadIdx.x;
  XCD_REMAP16(bx, by, z);
  A += (long long)z * aBatch;
  Bt += (long long)z * bBatch;
  const int m0 = by * 256, n0 = bx * 128;
  const int w = tid >> 6, l = tid & 63;
  const int lr = l & 15, quad = l >> 4;
  const int wm = w >> 1, wn = w & 1;

  const floatx4 fz = {0.f, 0.f, 0.f, 0.f};
  floatx4 acc[4][4];
#pragma unroll
  for (int i = 0; i < 4; i++)
#pragma unroll
    for (int j = 0; j < 4; j++) acc[i][j] = fz;

  const int r0 = tid >> 2;
  const int gq0 = (tid & 3) ^ ((tid >> 3) & 3);
  const half_t* aS0 = A + (long long)(m0 + r0) * lda + gq0 * 8;
  const half_t* aS1 = aS0 + (long long)128 * lda;
  const half_t* bS0 = Bt + (long long)(n0 + r0) * ldb + gq0 * 8;  // r0<128
  const int wso = w << 9;

  const int swz = (quad ^ ((lr >> 1) & 3)) << 3;
  const int aBase = wm * 2048 + lr * 32 + swz;
  const int bBase = wn * 2048 + lr * 32 + swz;
  const int NT = K >> 5;

#define SA(BUF, KOFF) do { half_t* d_ = &As[(BUF) * 8192 + wso]; \
    gload16(aS0 + (KOFF), d_); gload16(aS1 + (KOFF), d_ + 4096); } while (0)
#define SB(BUF, KOFF) do { half_t* d_ = &Bs[(BUF) * 4096 + wso]; \
    gload16(bS0 + (KOFF), d_); } while (0)
#define LDA4(S, OFF) { const half_t* ap_ = &As[(OFF)]; \
    S##0 = *(const short8*)(ap_); S##1 = *(const short8*)(ap_ + 512); \
    S##2 = *(const short8*)(ap_ + 1024); S##3 = *(const short8*)(ap_ + 1536); }
#define LDB4(S, OFF) { const half_t* bp_ = &Bs[(OFF)]; \
    S##0 = *(const short8*)(bp_); S##1 = *(const short8*)(bp_ + 512); \
    S##2 = *(const short8*)(bp_ + 1024); S##3 = *(const short8*)(bp_ + 1536); }
#define MFMA16(AS, BS) do { \
    acc[0][0] = __builtin_amdgcn_mfma_f32_16x16x32_f16(AS##0, BS##0, acc[0][0], 0, 0, 0); \
    acc[0][1] = __builtin_amdgcn_mfma_f32_16x16x32_f16(AS##0, BS##1, acc[0][1], 0, 0, 0); \
    acc[0][2] = __builtin_amdgcn_mfma_f32_16x16x32_f16(AS##0, BS##2, acc[0][2], 0, 0, 0); \
    acc[0][3] = __builtin_amdgcn_mfma_f32_16x16x32_f16(AS##0, BS##3, acc[0][3], 0, 0, 0); \
    acc[1][0] = __builtin_amdgcn_mfma_f32_16x16x32_f16(AS##1, BS##0, acc[1][0], 0, 0, 0); \
    acc[1][1] = __builtin_amdgcn_mfma_f32_16x16x32_f16(AS##1, BS##1, acc[1][1], 0, 0, 0); \
    acc[1][2] = __builtin_amdgcn_mfma_f32_16x16x32_f16(AS##1, BS##2, acc[1][2], 0, 0, 0); \
    acc[1][3] = __builtin_amdgcn_mfma_f32_16x16x32_f16(AS##1, BS##3, acc[1][3], 0, 0, 0); \
    acc[2][0] = __builtin_amdgcn_mfma_f32_16x16x32_f16(AS##2, BS##0, acc[2][0], 0, 0, 0); \
    acc[2][1] = __builtin_amdgcn_mfma_f32_16x16x32_f16(AS##2, BS##1, acc[2][1], 0, 0, 0); \
    acc[2][2] = __builtin_amdgcn_mfma_f32_16x16x32_f16(AS##2, BS##2, acc[2][2], 0, 0, 0); \
    acc[2][3] = __builtin_amdgcn_mfma_f32_16x16x32_f16(AS##2, BS##3, acc[2][3], 0, 0, 0); \
    acc[3][0] = __builtin_amdgcn_mfma_f32_16x16x32_f16(AS##3, BS##0, acc[3][0], 0, 0, 0); \
    acc[3][1] = __builtin_amdgcn_mfma_f32_16x16x32_f16(AS##3, BS##1, acc[3][1], 0, 0, 0); \
    acc[3][2] = __builtin_amdgcn_mfma_f32_16x16x32_f16(AS##3, BS##2, acc[3][2], 0, 0, 0); \
    acc[3][3] = __builtin_amdgcn_mfma_f32_16x16x32_f16(AS##3, BS##3, acc[3][3], 0, 0, 0); \
  } while (0)

  SA(0, 0); SB(0, 0);
  SA(1, 32); SB(1, 32);
  VM3();
  BAR();

  int cur = 0;
  for (int t = 0; t < NT; ++t) {
    short8 aA0, aA1, aA2, aA3, bA0, bA1, bA2, bA3;
    LDA4(aA, cur * 8192 + aBase);
    LDB4(bA, cur * 4096 + bBase);
    if (t + 2 < NT) {
      const int sb = (cur >= 1) ? cur - 1 : 2;  // (cur+2)%3
      SA(sb, (t + 2) * 32);
      SB(sb, (t + 2) * 32);
      VM3();
    } else if (t == NT - 2) {
      VM0();
    }
    BAR();
    LGKM0();
    __builtin_amdgcn_s_setprio(1);
    MFMA16(aA, bA);
    __builtin_amdgcn_s_setprio(0);
    cur = (cur == 2) ? 0 : cur + 1;
  }

#pragma unroll
  for (int i = 0; i < 4; i++) {
#pragma unroll
    for (int j = 0; j < 4; j++) {
#pragma unroll
      for (int r = 0; r < 4; r++) {
        int grow = m0 + wm * 64 + i * 16 + quad * 4 + r;
        int gcol = n0 + wn * 64 + j * 16 + lr;
        float v = acc[i][j][r];
        if (MODE == EP_F32) {
          float* C = (float*)Cout + (long long)z * cBatch;
          C[(long long)grow * ldc + gcol] = v;
        } else {  // EP_QK, interleaved pair layout: row pos 2u,2u+1
          int sel = gcol >> 10;
          int ucol = gcol & 1023;
          half_t h = (half_t)v;
          unsigned hu = h2u(h);
          unsigned val;
          half_t* base;
          if (sel == 0) {  // Q: [qh, ql] pairs
            val = hu | ((unsigned)h2u((half_t)(v - (float)h)) << 16);
            base = (half_t*)Cout;
          } else {         // K: [kh, kh] pairs
            val = hu | (hu << 16);
            base = CoutK;
          }
          *(unsigned*)(base + (long long)grow * KCAT + 2 * ucol) = val;
        }
      }
    }
  }
#undef SA
#undef SB
#undef LDA4
#undef LDB4
#undef MFMA16
}

// ---------- softmax, in place: S row (fp32[2048]) -> P row (fp16[2048]) ----------
__global__ __launch_bounds__(256) void k_softmax(float* __restrict__ Sbuf) {
  long long row = blockIdx.x;  // 0..8191
  float* p = Sbuf + row * 2048;
  int t = threadIdx.x;
  float4 v0 = ((const float4*)p)[t];
  float4 v1 = ((const float4*)p)[t + 256];
  float m = fmaxf(fmaxf(fmaxf(v0.x, v0.y), fmaxf(v0.z, v0.w)),
                  fmaxf(fmaxf(v1.x, v1.y), fmaxf(v1.z, v1.w)));
  for (int off = 32; off; off >>= 1) m = fmaxf(m, __shfl_xor(m, off));
  __shared__ float red[8];
  int wv = t >> 6, ln = t & 63;
  if (ln == 0) red[wv] = m;
  __syncthreads();
  m = fmaxf(fmaxf(red[0], red[1]), fmaxf(red[2], red[3]));
  float e0 = __expf(v0.x - m), e1 = __expf(v0.y - m), e2 = __expf(v0.z - m), e3 = __expf(v0.w - m);
  float e4 = __expf(v1.x - m), e5 = __expf(v1.y - m), e6 = __expf(v1.z - m), e7 = __expf(v1.w - m);
  float s = ((e0 + e1) + (e2 + e3)) + ((e4 + e5) + (e6 + e7));
  for (int off = 32; off; off >>= 1) s += __shfl_xor(s, off);
  if (ln == 0) red[4 + wv] = s;
  __syncthreads();
  s = (red[4] + red[5]) + (red[6] + red[7]);
  float inv = 1.0f / s;
  uint2 w0, w1;
  w0.x = (unsigned)h2u((half_t)(e0 * inv)) | ((unsigned)h2u((half_t)(e1 * inv)) << 16);
  w0.y = (unsigned)h2u((half_t)(e2 * inv)) | ((unsigned)h2u((half_t)(e3 * inv)) << 16);
  w1.x = (unsigned)h2u((half_t)(e4 * inv)) | ((unsigned)h2u((half_t)(e5 * inv)) << 16);
  w1.y = (unsigned)h2u((half_t)(e6 * inv)) | ((unsigned)h2u((half_t)(e7 * inv)) << 16);
  ((uint2*)p)[t] = w0;
  ((uint2*)p)[t + 256] = w1;
}

// ---------- host launch ----------
extern "C" void kernel_launch(void* const* d_in, const int* in_sizes, int n_in,
                              void* d_out, int out_size, void* d_ws, size_t ws_size,
                              hipStream_t stream) {
  (void)in_sizes; (void)n_in; (void)out_size;
  if (ws_size < WS_NEED) return;  // output stays poisoned -> visible failure

  const float* X = (const float*)d_in[0];
  const float* Wq = (const float*)d_in[1];
  const float* Wk = (const float*)d_in[2];
  const float* Wv = (const float*)d_in[3];
  char* ws = (char*)d_ws;
  half_t* xcat = (half_t*)(ws + XCAT_OFF);
  half_t* wt = (half_t*)(ws + WT_OFF);
  float* Sbuf = (float*)(ws + S_OFF);
  half_t* qcat = (half_t*)(ws + QCAT_OFF);
  half_t* kcat = (half_t*)(ws + KCAT_OFF);
  half_t* vt = (half_t*)(ws + VT_OFF);
  float* out = (float*)d_out;

  // 1. split X and W (fp16)
  k_split_x<<<dim3(MX * 1024 / 256), dim3(256), 0, stream>>>(X, xcat);
  k_split_wt<<<dim3(16, 16, 3), dim3(256), 0, stream>>>(Wq, Wk, Wv, wt);

  // 2a. fused QK projection: M=8192, N=2048 (Wq|Wk), K=2048 (2-term)
  //     256x128 tiles -> (16, 32) = 512 blocks = 2/CU.
  k_gemm256<EP_QK><<<dim3(16, 32, 1), dim3(512), 0, stream>>>(
      xcat, 0LL, KCAT, wt, 0LL, KCAT, qcat, 0LL, 0, KCAT, kcat);

  // 2b. V projection: M=8192, N=1024, K=1024 (1-term) -- 128x64, 4 blocks/CU
  k_gemm64<EP_VT><<<dim3(16, 64, 1), dim3(256), 0, stream>>>(
      xcat, 0LL, KCAT, wt + 2 * 1024 * KCAT, 0LL, KCAT, vt, 0LL, 0, 1024);

  // 3. scores S = Q K^T (fp16 2-term, interleaved k-layout on both sides)
  //    per batch (16, 8) x 4 = 512 blocks = 2/CU.
  k_gemm256<EP_F32><<<dim3(16, 8, 4), dim3(512), 0, stream>>>(
      qcat, (long long)2048 * KCAT, KCAT, kcat, (long long)2048 * KCAT, KCAT,
      Sbuf, (long long)2048 * 2048, 2048, KCAT, nullptr);

  // 4. softmax in place (fp32 row -> fp16 row; row stride becomes 4096 halves)
  k_softmax<<<dim3(8192), dim3(256), 0, stream>>>(Sbuf);

  // 5. O = P V (plain fp16), fp32 out: 128x64 tiles -> (16,16,4) = 1024
  //    blocks = 4/CU (was 512 = 2/CU: the 424 TF cliff).
  k_gemm64<EP_F32><<<dim3(16, 16, 4), dim3(256), 0, stream>>>(
      (const half_t*)Sbuf, (long long)2048 * 4096, 4096,
      vt, (long long)1024 * 2048, 2048,
      out, (long long)2048 * 1024, 1024, 2048);
}